// Round 3
// baseline (243.924 us; speedup 1.0000x reference)
//
#include <hip/hip_runtime.h>
#include <math.h>

#define NTOK 8192
#define DD   2048
#define EE   64
#define KSPLIT 4
#define DPER (DD/KSPLIT)        // 512 d-values per block
#define NCHUNK (DPER/32)        // 16 chunks of 32 d
#define FTOT (2*DD)             // 4096 features
#define WT_SSTRIDE (EE*FTOT)    // elements per split plane
#define PROB_N (NTOK*2)

typedef __bf16 bf16x8 __attribute__((ext_vector_type(8)));
typedef float  f32x4  __attribute__((ext_vector_type(4)));
typedef unsigned short u16x8 __attribute__((ext_vector_type(8)));

// RNE fp32 -> bf16 bits + the representable float it denotes
__device__ __forceinline__ unsigned short bf16_rne(float x, float& rep) {
    unsigned u = __builtin_bit_cast(unsigned, x);
    unsigned r = u + 0x7FFFu + ((u >> 16) & 1u);
    unsigned short h = (unsigned short)(r >> 16);
    rep = __builtin_bit_cast(float, (unsigned)h << 16);
    return h;
}

// 3-way bf16 split: x = h1 + h2 + h3 + eps, |eps| <~ 2^-27 |x|
__device__ __forceinline__ void split3(float x, unsigned short& h1,
                                       unsigned short& h2, unsigned short& h3) {
    float f1, f2, f3;
    h1 = bf16_rne(x, f1);
    float r1 = x - f1;
    h2 = bf16_rne(r1, f2);
    float r2 = r1 - f2;
    h3 = bf16_rne(r2, f3);
}

// Kernel 0: split W [4096][64] fp32 -> Wt [3][64][4096] bf16 (expert-major),
// with coalesced 16B stores; also zero the score accumulator (2 MB).
__global__ __launch_bounds__(256) void wsplit(const float* __restrict__ W,
                                              unsigned short* __restrict__ Wt,
                                              float* __restrict__ score) {
    const int g  = blockIdx.x * 256 + threadIdx.x;   // 32768 threads
    const int e  = g >> 9;                            // expert 0..63
    const int f0 = (g & 511) * 8;                     // feature base
    u16x8 h1v, h2v, h3v;
    #pragma unroll
    for (int j = 0; j < 8; ++j) {
        unsigned short h1, h2, h3;
        split3(W[(size_t)(f0 + j) * EE + e], h1, h2, h3);
        h1v[j] = h1; h2v[j] = h2; h3v[j] = h3;
    }
    const size_t o = (size_t)e * FTOT + f0;
    *(u16x8*)&Wt[0 * WT_SSTRIDE + o] = h1v;
    *(u16x8*)&Wt[1 * WT_SSTRIDE + o] = h2v;
    *(u16x8*)&Wt[2 * WT_SSTRIDE + o] = h3v;

    // zero score buffer: 131072 float4s across 32768 threads
    float4* sz = (float4*)score;
    #pragma unroll
    for (int k = 0; k < 4; ++k)
        sz[(size_t)g * 4 + k] = make_float4(0.f, 0.f, 0.f, 0.f);
}

// Kernel 1: barrier-free MFMA gemm. Each wave: 16 tokens x 64 experts over a
// 512-d K-slice. A-fragments computed in-register (amp/phase/3-split of the
// lane's own 8 d-values); B-fragments straight from L1/L2. Zero LDS.
__global__ __launch_bounds__(256, 2) void gemm_mfma(
    const float* __restrict__ xr, const float* __restrict__ xi,
    const unsigned short* __restrict__ Wt, float* __restrict__ score)
{
    const int bid   = blockIdx.x;
    const int ks    = bid & (KSPLIT - 1);
    const int strip = bid >> 2;
    const int t0    = strip * 64;
    const int dbase = ks * DPER;

    const int tid  = threadIdx.x;
    const int wv   = tid >> 6;
    const int lane = tid & 63;
    const int fm   = lane & 15;    // A: token row; B/D: expert col
    const int fq   = lane >> 4;    // A/B: k-octet; D: row quad

    const int trow = t0 + wv * 16 + fm;
    const float* prx = xr + (size_t)trow * DD + dbase + fq * 8;
    const float* pix = xi + (size_t)trow * DD + dbase + fq * 8;
    const unsigned short* wb = Wt + (size_t)fm * FTOT + fq * 8;

    f32x4 acc[4];
    #pragma unroll
    for (int n = 0; n < 4; ++n) acc[n] = (f32x4){0.f, 0.f, 0.f, 0.f};

    float4 vr0 = *(const float4*)(prx);
    float4 vr1 = *(const float4*)(prx + 4);
    float4 vi0 = *(const float4*)(pix);
    float4 vi1 = *(const float4*)(pix + 4);

    for (int c = 0; c < NCHUNK; ++c) {
        const int d0 = dbase + c * 32;

        // prefetch next chunk's x
        const int off = ((c + 1 < NCHUNK) ? (c + 1) : c) * 32;
        const float4 nr0 = *(const float4*)(prx + off);
        const float4 nr1 = *(const float4*)(prx + off + 4);
        const float4 ni0 = *(const float4*)(pix + off);
        const float4 ni1 = *(const float4*)(pix + off + 4);

        // B fragments for both k-steps (amp features = d, phase = 2048+d)
        bf16x8 ba[4][3], bp[4][3];
        #pragma unroll
        for (int n = 0; n < 4; ++n)
            #pragma unroll
            for (int s = 0; s < 3; ++s) {
                const unsigned short* p = wb + (size_t)n * 16 * FTOT + (size_t)s * WT_SSTRIDE + d0;
                ba[n][s] = *(const bf16x8*)(p);
                bp[n][s] = *(const bf16x8*)(p + DD);
            }

        // amp/phase + 3-split, in-register A-fragments
        const float ar[8] = {vr0.x, vr0.y, vr0.z, vr0.w, vr1.x, vr1.y, vr1.z, vr1.w};
        const float ai[8] = {vi0.x, vi0.y, vi0.z, vi0.w, vi1.x, vi1.y, vi1.z, vi1.w};
        u16x8 ua[3], up[3];
        #pragma unroll
        for (int j = 0; j < 8; ++j) {
            const float amp = sqrtf(fmaf(ar[j], ar[j], ai[j] * ai[j]));
            const float ph  = atan2f(ai[j], ar[j]);
            unsigned short h1, h2, h3;
            split3(amp, h1, h2, h3);
            ua[0][j] = h1; ua[1][j] = h2; ua[2][j] = h3;
            split3(ph, h1, h2, h3);
            up[0][j] = h1; up[1][j] = h2; up[2][j] = h3;
        }
        const bf16x8 aa0 = __builtin_bit_cast(bf16x8, ua[0]);
        const bf16x8 aa1 = __builtin_bit_cast(bf16x8, ua[1]);
        const bf16x8 aa2 = __builtin_bit_cast(bf16x8, ua[2]);
        const bf16x8 ap0 = __builtin_bit_cast(bf16x8, up[0]);
        const bf16x8 ap1 = __builtin_bit_cast(bf16x8, up[1]);
        const bf16x8 ap2 = __builtin_bit_cast(bf16x8, up[2]);

        // 6 split-products per (n, k-step), all into one fp32 accumulator
        #pragma unroll
        for (int n = 0; n < 4; ++n) {
            acc[n] = __builtin_amdgcn_mfma_f32_16x16x32_bf16(aa0, ba[n][0], acc[n], 0, 0, 0);
            acc[n] = __builtin_amdgcn_mfma_f32_16x16x32_bf16(aa0, ba[n][1], acc[n], 0, 0, 0);
            acc[n] = __builtin_amdgcn_mfma_f32_16x16x32_bf16(aa1, ba[n][0], acc[n], 0, 0, 0);
            acc[n] = __builtin_amdgcn_mfma_f32_16x16x32_bf16(aa0, ba[n][2], acc[n], 0, 0, 0);
            acc[n] = __builtin_amdgcn_mfma_f32_16x16x32_bf16(aa1, ba[n][1], acc[n], 0, 0, 0);
            acc[n] = __builtin_amdgcn_mfma_f32_16x16x32_bf16(aa2, ba[n][0], acc[n], 0, 0, 0);
        }
        #pragma unroll
        for (int n = 0; n < 4; ++n) {
            acc[n] = __builtin_amdgcn_mfma_f32_16x16x32_bf16(ap0, bp[n][0], acc[n], 0, 0, 0);
            acc[n] = __builtin_amdgcn_mfma_f32_16x16x32_bf16(ap0, bp[n][1], acc[n], 0, 0, 0);
            acc[n] = __builtin_amdgcn_mfma_f32_16x16x32_bf16(ap1, bp[n][0], acc[n], 0, 0, 0);
            acc[n] = __builtin_amdgcn_mfma_f32_16x16x32_bf16(ap0, bp[n][2], acc[n], 0, 0, 0);
            acc[n] = __builtin_amdgcn_mfma_f32_16x16x32_bf16(ap1, bp[n][1], acc[n], 0, 0, 0);
            acc[n] = __builtin_amdgcn_mfma_f32_16x16x32_bf16(ap2, bp[n][0], acc[n], 0, 0, 0);
        }

        vr0 = nr0; vr1 = nr1; vi0 = ni0; vi1 = ni1;
    }

    // epilogue: D layout col=lane&15, row=(lane>>4)*4+reg [m89]
    // token = t0 + wv*16 + fq*4 + r, expert = n*16 + fm
    float* sb = score + (size_t)(t0 + wv * 16 + fq * 4) * EE + fm;
    #pragma unroll
    for (int n = 0; n < 4; ++n)
        #pragma unroll
        for (int r = 0; r < 4; ++r)
            atomicAdd(sb + (size_t)r * EE + n * 16, acc[n][r]);
}

// Kernel 2: per token add bias, exact top-2 via shuffle butterfly
// (tie-break lower index, matching lax.top_k), normalized probs + indices.
__global__ __launch_bounds__(256) void finalize_topk(
    const float* __restrict__ score, const float* __restrict__ bias,
    float* __restrict__ out)
{
    const int tid  = threadIdx.x;
    const int lane = tid & 63;   // = expert
    const int w    = tid >> 6;
    const int t    = blockIdx.x * 4 + w;

    float s = bias[lane] + score[(size_t)t * EE + lane];

    float v1 = s, v2 = -INFINITY;
    int   i1 = lane, i2 = 64;

    #pragma unroll
    for (int off = 1; off < 64; off <<= 1) {
        const float ov1 = __shfl_xor(v1, off, 64);
        const int   oi1 = __shfl_xor(i1, off, 64);
        const float ov2 = __shfl_xor(v2, off, 64);
        const int   oi2 = __shfl_xor(i2, off, 64);
        const bool b1 = (ov1 > v1) || (ov1 == v1 && oi1 < i1);
        const float n1 = b1 ? ov1 : v1;  const int ni1 = b1 ? oi1 : i1;
        const float c1 = b1 ? v1  : ov1; const int ci1 = b1 ? i1  : oi1;
        const float c2 = b1 ? ov2 : v2;  const int ci2 = b1 ? oi2 : i2;
        const bool b2 = (c1 > c2) || (c1 == c2 && ci1 < ci2);
        v1 = n1; i1 = ni1;
        v2 = b2 ? c1 : c2; i2 = b2 ? ci1 : ci2;
    }

    if (lane == 0) {
        const float z  = expf(v2 - v1);
        const float p1 = 1.0f / (1.0f + z);
        const float p2 = z / (1.0f + z);
        out[(size_t)t * 2 + 0] = p1;
        out[(size_t)t * 2 + 1] = p2;
        out[PROB_N + (size_t)t * 2 + 0] = (float)i1;
        out[PROB_N + (size_t)t * 2 + 1] = (float)i2;
    }
}

extern "C" void kernel_launch(void* const* d_in, const int* in_sizes, int n_in,
                              void* d_out, int out_size, void* d_ws, size_t ws_size,
                              hipStream_t stream) {
    const float* xr = (const float*)d_in[0];
    const float* xi = (const float*)d_in[1];
    const float* W  = (const float*)d_in[2];
    const float* b  = (const float*)d_in[3];
    float* out = (float*)d_out;

    float* score = (float*)d_ws;                                   // 2 MB
    unsigned short* Wt = (unsigned short*)((char*)d_ws + (size_t)NTOK * EE * 4);  // 1.5 MB

    wsplit<<<128, 256, 0, stream>>>(W, Wt, score);
    gemm_mfma<<<(NTOK / 64) * KSPLIT, 256, 0, stream>>>(xr, xi, Wt, score);
    finalize_topk<<<NTOK / 4, 256, 0, stream>>>(score, b, out);
}

// Round 4
// 197.378 us; speedup vs baseline: 1.2358x; 1.2358x over previous
//
#include <hip/hip_runtime.h>
#include <math.h>

#define NTOK 8192
#define DD   2048
#define EE   64
#define STRIP 16             // tokens per block
#define NKH 8                // K-slices = waves per block
#define DSLICE (DD/NKH)      // 256 d per wave
#define NCH (DSLICE/32)      // 8 chunks of 32 d per wave
#define PROB_N (NTOK*2)
// F (swizzled W) layout: [s:3][ck:128][nt:4][lane:64][j:8] bf16, 1.5 MB
#define F_SSTRIDE (128*4*64*8)   // 262144 elements per split plane

typedef __bf16 bf16x8 __attribute__((ext_vector_type(8)));
typedef float  f32x4  __attribute__((ext_vector_type(4)));
typedef unsigned short u16x8 __attribute__((ext_vector_type(8)));

// RNE fp32 -> bf16 bits + representable float
__device__ __forceinline__ unsigned short bf16_rne(float x, float& rep) {
    unsigned u = __builtin_bit_cast(unsigned, x);
    unsigned r = u + 0x7FFFu + ((u >> 16) & 1u);
    unsigned short h = (unsigned short)(r >> 16);
    rep = __builtin_bit_cast(float, (unsigned)h << 16);
    return h;
}
// 3-way bf16 split: x = h1+h2+h3+eps, |eps| <~ 2^-27 |x|
__device__ __forceinline__ void split3(float x, unsigned short& h1,
                                       unsigned short& h2, unsigned short& h3) {
    float f1, f2, f3;
    h1 = bf16_rne(x, f1);
    float r1 = x - f1;
    h2 = bf16_rne(r1, f2);
    float r2 = r1 - f2;
    h3 = bf16_rne(r2, f3);
}

// Kernel 0: split + swizzle W [4096][64] fp32 -> F fragment-order bf16.
// feature(amp,d) -> kstep 2*(d>>5), k=d&31; feature(phase,d) -> kstep 2*(d>>5)+1.
// element (expert e, k) sits at [nt=e>>4][lane=(k>>3)*16+(e&15)][j=k&7].
__global__ __launch_bounds__(256) void wsplit(const float* __restrict__ W,
                                              unsigned short* __restrict__ F) {
    const int g  = blockIdx.x * 256 + threadIdx.x;   // 32768 threads
    const int e  = g & 63;
    const int q  = g >> 6;          // 0..511
    const int d0 = q * 4;           // 4 consecutive d per thread
    const int nt = e >> 4;
    const int k  = d0 & 31;
    const int lane = (k >> 3) * 16 + (e & 15);
    const int j0 = k & 7;           // 0 or 4
    const int ck = 2 * (d0 >> 5);   // amp kstep; phase = ck+1

    unsigned short ah[3][4], ph[3][4];
    #pragma unroll
    for (int i = 0; i < 4; ++i) {
        split3(W[(size_t)(d0 + i) * EE + e],      ah[0][i], ah[1][i], ah[2][i]);
        split3(W[(size_t)(DD + d0 + i) * EE + e], ph[0][i], ph[1][i], ph[2][i]);
    }
    #pragma unroll
    for (int s = 0; s < 3; ++s) {
        ushort4 va = make_ushort4(ah[s][0], ah[s][1], ah[s][2], ah[s][3]);
        ushort4 vp = make_ushort4(ph[s][0], ph[s][1], ph[s][2], ph[s][3]);
        *(ushort4*)&F[(size_t)(((s * 128 + ck)     * 4 + nt) * 64 + lane) * 8 + j0] = va;
        *(ushort4*)&F[(size_t)(((s * 128 + ck + 1) * 4 + nt) * 64 + lane) * 8 + j0] = vp;
    }
}

// Kernel 1: fused gemm + reduce + top-2. Block = 16 tokens, 8 waves = 8
// K-slices x 64 experts. A-frags in-register (amp/phase/3-split of the lane's
// own 8 d); B-frags are contiguous 1KB wave loads from swizzled F. Epilogue:
// LDS tree-reduce 8 partials + bias, exact shuffle top-2, write outputs.
__global__ __launch_bounds__(512, 4) void gemm_topk(
    const float* __restrict__ xr, const float* __restrict__ xi,
    const unsigned short* __restrict__ F, const float* __restrict__ bias,
    float* __restrict__ out)
{
    __shared__ float score8[NKH][STRIP][EE];   // 32 KB
    __shared__ float scoreF[STRIP][EE];        // 4 KB

    const int tid  = threadIdx.x;
    const int wv   = tid >> 6;      // K-slice
    const int lane = tid & 63;
    const int fm   = lane & 15;     // A: token row; B: expert-in-tile; D: col
    const int fq   = lane >> 4;     // A/B: k-octet; D: row quad
    const int t0   = blockIdx.x * STRIP;

    const float* prx = xr + (size_t)(t0 + fm) * DD + wv * DSLICE + fq * 8;
    const float* pix = xi + (size_t)(t0 + fm) * DD + wv * DSLICE + fq * 8;
    // B pointers for the 3 split planes, at this wave's first kstep
    const unsigned short* bs0 = F + (size_t)(wv * NCH * 2) * 4 * 512 + lane * 8;
    const unsigned short* bs1 = bs0 + F_SSTRIDE;
    const unsigned short* bs2 = bs0 + 2 * F_SSTRIDE;

    f32x4 acc[4];
    #pragma unroll
    for (int n = 0; n < 4; ++n) acc[n] = (f32x4){0.f, 0.f, 0.f, 0.f};

    #pragma unroll 2
    for (int c = 0; c < NCH; ++c) {
        const float4 vr0 = *(const float4*)(prx);
        const float4 vr1 = *(const float4*)(prx + 4);
        const float4 vi0 = *(const float4*)(pix);
        const float4 vi1 = *(const float4*)(pix + 4);
        prx += 32; pix += 32;

        const float ar[8] = {vr0.x, vr0.y, vr0.z, vr0.w, vr1.x, vr1.y, vr1.z, vr1.w};
        const float ai[8] = {vi0.x, vi0.y, vi0.z, vi0.w, vi1.x, vi1.y, vi1.z, vi1.w};

        // phase 1: amp frags + st=0 MFMAs
        u16x8 u0, u1, u2;
        #pragma unroll
        for (int j = 0; j < 8; ++j) {
            const float amp = sqrtf(fmaf(ar[j], ar[j], ai[j] * ai[j]));
            unsigned short h1, h2, h3;
            split3(amp, h1, h2, h3);
            u0[j] = h1; u1[j] = h2; u2[j] = h3;
        }
        {
            const bf16x8 a1 = __builtin_bit_cast(bf16x8, u0);
            const bf16x8 a2 = __builtin_bit_cast(bf16x8, u1);
            const bf16x8 a3 = __builtin_bit_cast(bf16x8, u2);
            #pragma unroll
            for (int n = 0; n < 4; ++n) {
                const bf16x8 b1 = *(const bf16x8*)(bs0 + n * 512);
                const bf16x8 b2 = *(const bf16x8*)(bs1 + n * 512);
                const bf16x8 b3 = *(const bf16x8*)(bs2 + n * 512);
                acc[n] = __builtin_amdgcn_mfma_f32_16x16x32_bf16(a1, b1, acc[n], 0, 0, 0);
                acc[n] = __builtin_amdgcn_mfma_f32_16x16x32_bf16(a1, b2, acc[n], 0, 0, 0);
                acc[n] = __builtin_amdgcn_mfma_f32_16x16x32_bf16(a2, b1, acc[n], 0, 0, 0);
                acc[n] = __builtin_amdgcn_mfma_f32_16x16x32_bf16(a1, b3, acc[n], 0, 0, 0);
                acc[n] = __builtin_amdgcn_mfma_f32_16x16x32_bf16(a2, b2, acc[n], 0, 0, 0);
                acc[n] = __builtin_amdgcn_mfma_f32_16x16x32_bf16(a3, b1, acc[n], 0, 0, 0);
            }
        }
        // phase 2: phase frags + st=1 MFMAs
        #pragma unroll
        for (int j = 0; j < 8; ++j) {
            const float ph = atan2f(ai[j], ar[j]);
            unsigned short h1, h2, h3;
            split3(ph, h1, h2, h3);
            u0[j] = h1; u1[j] = h2; u2[j] = h3;
        }
        {
            const bf16x8 a1 = __builtin_bit_cast(bf16x8, u0);
            const bf16x8 a2 = __builtin_bit_cast(bf16x8, u1);
            const bf16x8 a3 = __builtin_bit_cast(bf16x8, u2);
            #pragma unroll
            for (int n = 0; n < 4; ++n) {
                const bf16x8 b1 = *(const bf16x8*)(bs0 + (4 + n) * 512);
                const bf16x8 b2 = *(const bf16x8*)(bs1 + (4 + n) * 512);
                const bf16x8 b3 = *(const bf16x8*)(bs2 + (4 + n) * 512);
                acc[n] = __builtin_amdgcn_mfma_f32_16x16x32_bf16(a1, b1, acc[n], 0, 0, 0);
                acc[n] = __builtin_amdgcn_mfma_f32_16x16x32_bf16(a1, b2, acc[n], 0, 0, 0);
                acc[n] = __builtin_amdgcn_mfma_f32_16x16x32_bf16(a2, b1, acc[n], 0, 0, 0);
                acc[n] = __builtin_amdgcn_mfma_f32_16x16x32_bf16(a1, b3, acc[n], 0, 0, 0);
                acc[n] = __builtin_amdgcn_mfma_f32_16x16x32_bf16(a2, b2, acc[n], 0, 0, 0);
                acc[n] = __builtin_amdgcn_mfma_f32_16x16x32_bf16(a3, b1, acc[n], 0, 0, 0);
            }
        }
        bs0 += 8 * 512; bs1 += 8 * 512; bs2 += 8 * 512;   // next 2 ksteps
    }

    // partials to LDS: D layout col=lane&15 (expert), row=(lane>>4)*4+reg (token)
    #pragma unroll
    for (int n = 0; n < 4; ++n)
        #pragma unroll
        for (int r = 0; r < 4; ++r)
            score8[wv][fq * 4 + r][n * 16 + fm] = acc[n][r];
    __syncthreads();

    // reduce 8 K-slices + bias
    #pragma unroll
    for (int rep = 0; rep < 2; ++rep) {
        const int p = tid + rep * 512;
        const int tok = p >> 6, e = p & 63;
        float s = bias[e];
        #pragma unroll
        for (int w = 0; w < NKH; ++w) s += score8[w][tok][e];
        scoreF[tok][e] = s;
    }
    __syncthreads();

    // exact top-2 (tie-break lower index, matching lax.top_k); 2 tokens/wave
    #pragma unroll
    for (int rep = 0; rep < 2; ++rep) {
        const int tok = wv + rep * 8;
        float v1 = scoreF[tok][lane], v2 = -INFINITY;
        int   i1 = lane, i2 = 64;
        #pragma unroll
        for (int off = 1; off < 64; off <<= 1) {
            const float ov1 = __shfl_xor(v1, off, 64);
            const int   oi1 = __shfl_xor(i1, off, 64);
            const float ov2 = __shfl_xor(v2, off, 64);
            const int   oi2 = __shfl_xor(i2, off, 64);
            const bool b1 = (ov1 > v1) || (ov1 == v1 && oi1 < i1);
            const float n1 = b1 ? ov1 : v1;  const int ni1 = b1 ? oi1 : i1;
            const float c1 = b1 ? v1  : ov1; const int ci1 = b1 ? i1  : oi1;
            const float c2 = b1 ? ov2 : v2;  const int ci2 = b1 ? oi2 : i2;
            const bool b2 = (c1 > c2) || (c1 == c2 && ci1 < ci2);
            v1 = n1; i1 = ni1;
            v2 = b2 ? c1 : c2; i2 = b2 ? ci1 : ci2;
        }
        if (lane == 0) {
            const int t = t0 + tok;
            const float z  = expf(v2 - v1);
            const float p1 = 1.0f / (1.0f + z);
            const float p2 = z / (1.0f + z);
            out[(size_t)t * 2 + 0] = p1;
            out[(size_t)t * 2 + 1] = p2;
            out[PROB_N + (size_t)t * 2 + 0] = (float)i1;
            out[PROB_N + (size_t)t * 2 + 1] = (float)i2;
        }
    }
}

extern "C" void kernel_launch(void* const* d_in, const int* in_sizes, int n_in,
                              void* d_out, int out_size, void* d_ws, size_t ws_size,
                              hipStream_t stream) {
    const float* xr = (const float*)d_in[0];
    const float* xi = (const float*)d_in[1];
    const float* W  = (const float*)d_in[2];
    const float* b  = (const float*)d_in[3];
    float* out = (float*)d_out;
    unsigned short* F = (unsigned short*)d_ws;   // 1.5 MB swizzled split-W

    wsplit<<<128, 256, 0, stream>>>(W, F);
    gemm_topk<<<NTOK / STRIP, 512, 0, stream>>>(xr, xi, F, b, out);
}

// Round 5
// 187.586 us; speedup vs baseline: 1.3003x; 1.0522x over previous
//
#include <hip/hip_runtime.h>
#include <math.h>

#define NTOK 8192
#define DD   2048
#define EE   64
#define STRIP 16             // tokens per block
#define NKH 8                // K-slices = waves per block
#define DSLICE (DD/NKH)      // 256 d per wave
#define NCH (DSLICE/32)      // 8 chunks of 32 d per wave
#define PROB_N (NTOK*2)
// F (swizzled W) layout: [s:3][ck:128][nt:4][lane:64][j:8] bf16, 1.5 MB
#define F_SSTRIDE (128*4*64*8)   // elements per split plane

typedef __bf16 bf16x8 __attribute__((ext_vector_type(8)));
typedef float  f32x4  __attribute__((ext_vector_type(4)));
typedef unsigned int u32x4 __attribute__((ext_vector_type(4)));

// exact truncation 3-split: x = f1 + f2 + f3 (8+8+8 mantissa bits), scalar form
__device__ __forceinline__ void tsplit3(float x, unsigned short& h1,
                                        unsigned short& h2, unsigned short& h3) {
    const unsigned u = __builtin_bit_cast(unsigned, x);
    h1 = (unsigned short)(u >> 16);
    const float f1 = __builtin_bit_cast(float, u & 0xFFFF0000u);
    const float r1 = x - f1;
    const unsigned v = __builtin_bit_cast(unsigned, r1);
    h2 = (unsigned short)(v >> 16);
    const float f2 = __builtin_bit_cast(float, v & 0xFFFF0000u);
    const float r2 = r1 - f2;          // exactly representable in bf16
    h3 = (unsigned short)(__builtin_bit_cast(unsigned, r2) >> 16);
}

// fast branchless atan2, ~1-2 ulp abs (Cephes reduction + deg-7 odd minimax)
__device__ __forceinline__ float fast_atan2f(float y, float x) {
    const float ax = __builtin_fabsf(x), ay = __builtin_fabsf(y);
    const float hi = fmaxf(ax, ay), lo = fminf(ax, ay);
    const bool  big = lo > 0.4142135679721832f * hi;       // tan(pi/8)
    const float num = big ? (lo - hi) : lo;
    const float den = big ? (lo + hi) : hi;
    float rc = __builtin_amdgcn_rcpf(den);
    rc = rc * fmaf(-den, rc, 2.0f);                        // 1 NR step
    const float z  = num * rc;                             // in [-0.293, 0.414]
    const float z2 = z * z;
    float p = fmaf(z2, 8.05374449538e-2f, -1.38776856032e-1f);
    p = fmaf(z2, p, 1.99777106478e-1f);
    p = fmaf(z2, p, -3.33329491539e-1f);
    float r = fmaf(z * z2, p, z);                          // atan(z)
    r = r + (big ? 0.78539816339744830962f : 0.0f);        // atan(lo/hi)
    r = (ay > ax) ? (1.57079632679489661923f - r) : r;     // atan2(ay,ax)
    r = (x < 0.0f) ? (3.14159265358979323846f - r) : r;    // atan2(ay,x)
    return copysignf(r, y);
}

// pack high-16s of two fp32 into one dword: [lo.hi16, hi.hi16]
__device__ __forceinline__ unsigned packhi(float a, float b) {
    return __builtin_amdgcn_perm(__builtin_bit_cast(unsigned, b),
                                 __builtin_bit_cast(unsigned, a), 0x07060302u);
}

// Build 3 bf16x8 split planes from 8 fp32 values (truncation split, exact)
__device__ __forceinline__ void split_planes(const float* v, bf16x8& o1,
                                             bf16x8& o2, bf16x8& o3) {
    u32x4 P1, P2, P3;
    #pragma unroll
    for (int p = 0; p < 4; ++p) {
        const float a = v[2 * p], b = v[2 * p + 1];
        const float f1a = __builtin_bit_cast(float, __builtin_bit_cast(unsigned, a) & 0xFFFF0000u);
        const float f1b = __builtin_bit_cast(float, __builtin_bit_cast(unsigned, b) & 0xFFFF0000u);
        const float r1a = a - f1a, r1b = b - f1b;
        const float f2a = __builtin_bit_cast(float, __builtin_bit_cast(unsigned, r1a) & 0xFFFF0000u);
        const float f2b = __builtin_bit_cast(float, __builtin_bit_cast(unsigned, r1b) & 0xFFFF0000u);
        const float r2a = r1a - f2a, r2b = r1b - f2b;
        P1[p] = packhi(a, b);
        P2[p] = packhi(r1a, r1b);
        P3[p] = packhi(r2a, r2b);
    }
    o1 = __builtin_bit_cast(bf16x8, P1);
    o2 = __builtin_bit_cast(bf16x8, P2);
    o3 = __builtin_bit_cast(bf16x8, P3);
}

// Kernel 0: split + swizzle W [4096][64] fp32 -> F fragment-order bf16.
__global__ __launch_bounds__(256) void wsplit(const float* __restrict__ W,
                                              unsigned short* __restrict__ F) {
    const int g  = blockIdx.x * 256 + threadIdx.x;   // 32768 threads
    const int e  = g & 63;
    const int q  = g >> 6;          // 0..511
    const int d0 = q * 4;           // 4 consecutive d per thread
    const int nt = e >> 4;
    const int k  = d0 & 31;
    const int lane = (k >> 3) * 16 + (e & 15);
    const int j0 = k & 7;           // 0 or 4
    const int ck = 2 * (d0 >> 5);   // amp kstep; phase = ck+1

    unsigned short ah[3][4], ph[3][4];
    #pragma unroll
    for (int i = 0; i < 4; ++i) {
        tsplit3(W[(size_t)(d0 + i) * EE + e],      ah[0][i], ah[1][i], ah[2][i]);
        tsplit3(W[(size_t)(DD + d0 + i) * EE + e], ph[0][i], ph[1][i], ph[2][i]);
    }
    #pragma unroll
    for (int s = 0; s < 3; ++s) {
        ushort4 va = make_ushort4(ah[s][0], ah[s][1], ah[s][2], ah[s][3]);
        ushort4 vp = make_ushort4(ph[s][0], ph[s][1], ph[s][2], ph[s][3]);
        *(ushort4*)&F[(size_t)(((s * 128 + ck)     * 4 + nt) * 64 + lane) * 8 + j0] = va;
        *(ushort4*)&F[(size_t)(((s * 128 + ck + 1) * 4 + nt) * 64 + lane) * 8 + j0] = vp;
    }
}

// Kernel 1: fused gemm + reduce + top-2, explicit x software pipeline.
__global__ __launch_bounds__(512, 4) void gemm_topk(
    const float* __restrict__ xr, const float* __restrict__ xi,
    const unsigned short* __restrict__ F, const float* __restrict__ bias,
    float* __restrict__ out)
{
    __shared__ float score8[NKH][STRIP][EE];   // 32 KB
    __shared__ float scoreF[STRIP][EE];        // 4 KB

    const int tid  = threadIdx.x;
    const int wv   = tid >> 6;      // K-slice
    const int lane = tid & 63;
    const int fm   = lane & 15;     // A: token row; D: col
    const int fq   = lane >> 4;     // A/B: k-octet; D: row quad
    const int t0   = blockIdx.x * STRIP;

    const float* prx = xr + (size_t)(t0 + fm) * DD + wv * DSLICE + fq * 8;
    const float* pix = xi + (size_t)(t0 + fm) * DD + wv * DSLICE + fq * 8;
    const unsigned short* bs0 = F + (size_t)(wv * NCH * 2) * 4 * 512 + lane * 8;
    const unsigned short* bs1 = bs0 + F_SSTRIDE;
    const unsigned short* bs2 = bs0 + 2 * F_SSTRIDE;

    f32x4 acc[4];
    #pragma unroll
    for (int n = 0; n < 4; ++n) acc[n] = (f32x4){0.f, 0.f, 0.f, 0.f};

    // pipeline prologue: chunk 0's x in registers
    float4 cr0 = *(const float4*)(prx);
    float4 cr1 = *(const float4*)(prx + 4);
    float4 ci0 = *(const float4*)(pix);
    float4 ci1 = *(const float4*)(pix + 4);
    prx += 32; pix += 32;

    #pragma unroll 2
    for (int c = 0; c < NCH; ++c) {
        // issue next chunk's x FIRST (oldest in vmcnt queue -> B waits skip it)
        float4 nr0, nr1, ni0, ni1;
        if (c + 1 < NCH) {          // uniform branch
            nr0 = *(const float4*)(prx);
            nr1 = *(const float4*)(prx + 4);
            ni0 = *(const float4*)(pix);
            ni1 = *(const float4*)(pix + 4);
            prx += 32; pix += 32;
        } else {
            nr0 = cr0; nr1 = cr1; ni0 = ci0; ni1 = ci1;
        }

        const float ar[8] = {cr0.x, cr0.y, cr0.z, cr0.w, cr1.x, cr1.y, cr1.z, cr1.w};
        const float ai[8] = {ci0.x, ci0.y, ci0.z, ci0.w, ci1.x, ci1.y, ci1.z, ci1.w};

        // ---- phase 0: amp ksteps ----
        {
            bf16x8 b1[4], b2[4], b3[4];
            #pragma unroll
            for (int n = 0; n < 4; ++n) {
                b1[n] = *(const bf16x8*)(bs0 + n * 512);
                b2[n] = *(const bf16x8*)(bs1 + n * 512);
                b3[n] = *(const bf16x8*)(bs2 + n * 512);
            }
            float av[8];
            #pragma unroll
            for (int j = 0; j < 8; ++j)
                av[j] = sqrtf(fmaf(ar[j], ar[j], ai[j] * ai[j]));
            bf16x8 a1, a2, a3;
            split_planes(av, a1, a2, a3);
            #pragma unroll
            for (int n = 0; n < 4; ++n) {
                acc[n] = __builtin_amdgcn_mfma_f32_16x16x32_bf16(a1, b1[n], acc[n], 0, 0, 0);
                acc[n] = __builtin_amdgcn_mfma_f32_16x16x32_bf16(a1, b2[n], acc[n], 0, 0, 0);
                acc[n] = __builtin_amdgcn_mfma_f32_16x16x32_bf16(a2, b1[n], acc[n], 0, 0, 0);
                acc[n] = __builtin_amdgcn_mfma_f32_16x16x32_bf16(a1, b3[n], acc[n], 0, 0, 0);
                acc[n] = __builtin_amdgcn_mfma_f32_16x16x32_bf16(a2, b2[n], acc[n], 0, 0, 0);
                acc[n] = __builtin_amdgcn_mfma_f32_16x16x32_bf16(a3, b1[n], acc[n], 0, 0, 0);
            }
        }
        // ---- phase 1: phase ksteps ----
        {
            bf16x8 b1[4], b2[4], b3[4];
            #pragma unroll
            for (int n = 0; n < 4; ++n) {
                b1[n] = *(const bf16x8*)(bs0 + (4 + n) * 512);
                b2[n] = *(const bf16x8*)(bs1 + (4 + n) * 512);
                b3[n] = *(const bf16x8*)(bs2 + (4 + n) * 512);
            }
            float pv[8];
            #pragma unroll
            for (int j = 0; j < 8; ++j)
                pv[j] = fast_atan2f(ai[j], ar[j]);
            bf16x8 a1, a2, a3;
            split_planes(pv, a1, a2, a3);
            #pragma unroll
            for (int n = 0; n < 4; ++n) {
                acc[n] = __builtin_amdgcn_mfma_f32_16x16x32_bf16(a1, b1[n], acc[n], 0, 0, 0);
                acc[n] = __builtin_amdgcn_mfma_f32_16x16x32_bf16(a1, b2[n], acc[n], 0, 0, 0);
                acc[n] = __builtin_amdgcn_mfma_f32_16x16x32_bf16(a2, b1[n], acc[n], 0, 0, 0);
                acc[n] = __builtin_amdgcn_mfma_f32_16x16x32_bf16(a1, b3[n], acc[n], 0, 0, 0);
                acc[n] = __builtin_amdgcn_mfma_f32_16x16x32_bf16(a2, b2[n], acc[n], 0, 0, 0);
                acc[n] = __builtin_amdgcn_mfma_f32_16x16x32_bf16(a3, b1[n], acc[n], 0, 0, 0);
            }
        }
        bs0 += 8 * 512; bs1 += 8 * 512; bs2 += 8 * 512;
        cr0 = nr0; cr1 = nr1; ci0 = ni0; ci1 = ni1;
    }

    // partials to LDS: D layout col=lane&15 (expert), row=(lane>>4)*4+reg (token)
    #pragma unroll
    for (int n = 0; n < 4; ++n)
        #pragma unroll
        for (int r = 0; r < 4; ++r)
            score8[wv][fq * 4 + r][n * 16 + fm] = acc[n][r];
    __syncthreads();

    // reduce 8 K-slices + bias
    #pragma unroll
    for (int rep = 0; rep < 2; ++rep) {
        const int p = tid + rep * 512;
        const int tok = p >> 6, e = p & 63;
        float s = bias[e];
        #pragma unroll
        for (int w = 0; w < NKH; ++w) s += score8[w][tok][e];
        scoreF[tok][e] = s;
    }
    __syncthreads();

    // exact top-2 (tie-break lower index, matching lax.top_k); 2 tokens/wave
    #pragma unroll
    for (int rep = 0; rep < 2; ++rep) {
        const int tok = wv + rep * 8;
        float v1 = scoreF[tok][lane], v2 = -INFINITY;
        int   i1 = lane, i2 = 64;
        #pragma unroll
        for (int off = 1; off < 64; off <<= 1) {
            const float ov1 = __shfl_xor(v1, off, 64);
            const int   oi1 = __shfl_xor(i1, off, 64);
            const float ov2 = __shfl_xor(v2, off, 64);
            const int   oi2 = __shfl_xor(i2, off, 64);
            const bool b1 = (ov1 > v1) || (ov1 == v1 && oi1 < i1);
            const float n1 = b1 ? ov1 : v1;  const int ni1 = b1 ? oi1 : i1;
            const float c1 = b1 ? v1  : ov1; const int ci1 = b1 ? i1  : oi1;
            const float c2 = b1 ? ov2 : v2;  const int ci2 = b1 ? oi2 : i2;
            const bool b2 = (c1 > c2) || (c1 == c2 && ci1 < ci2);
            v1 = n1; i1 = ni1;
            v2 = b2 ? c1 : c2; i2 = b2 ? ci1 : ci2;
        }
        if (lane == 0) {
            const int t = t0 + tok;
            const float z  = expf(v2 - v1);
            const float p1 = 1.0f / (1.0f + z);
            const float p2 = z / (1.0f + z);
            out[(size_t)t * 2 + 0] = p1;
            out[(size_t)t * 2 + 1] = p2;
            out[PROB_N + (size_t)t * 2 + 0] = (float)i1;
            out[PROB_N + (size_t)t * 2 + 1] = (float)i2;
        }
    }
}

extern "C" void kernel_launch(void* const* d_in, const int* in_sizes, int n_in,
                              void* d_out, int out_size, void* d_ws, size_t ws_size,
                              hipStream_t stream) {
    const float* xr = (const float*)d_in[0];
    const float* xi = (const float*)d_in[1];
    const float* W  = (const float*)d_in[2];
    const float* b  = (const float*)d_in[3];
    float* out = (float*)d_out;
    unsigned short* F = (unsigned short*)d_ws;   // 1.5 MB swizzled split-W

    wsplit<<<128, 256, 0, stream>>>(W, F);
    gemm_topk<<<NTOK / STRIP, 512, 0, stream>>>(xr, xi, F, b, out);
}